// Round 11
// baseline (1285.786 us; speedup 1.0000x reference)
//
#include <hip/hip_runtime.h>
#include <hip/hip_bf16.h>
#include <math.h>

#define NJ 22
#define MROWS 44          // 2 items x 22 joints per block
#define PROWS 48          // padded rows (3 row-tiles of 16)
#define NRT 3

typedef float f4 __attribute__((ext_vector_type(4)));
typedef _Float16 h8 __attribute__((ext_vector_type(8)));

// ---- d_ws layout (floats) ----
// P[2816] | FQE[960] (W'[4][192], b'[192]) | FSE[768] (W'[3][192], b'[192]) |
// fp16 weight planes (hi [N][K], then lo [N][K]) at half-offsets below
#define WOFF_QE_QKV 0        // (unused by fused; kept in split for layout)
#define WOFF_QE_O   24576    // K=64  N=256
#define WOFF_QE_M1  57344    // K=256 N=512
#define WOFF_QE_M2  319488   // K=512 N=256
#define WOFF_SE_QKV 581632
#define WOFF_SE_O   606208   // K=64  N=128
#define WOFF_SE_M1  622592   // K=128 N=256
#define WOFF_SE_M2  688128   // K=256 N=128
#define WOFF_EMB    753664   // K=512 N=128
#define W_TOTAL     884736   // halfs (incl emb hi+lo)

// LDS (~76.5K/block -> 2 blocks/CU):
//  XH: X fp16 plane [48][256] swizzled; finally QE's out_enc (cat cols 0:256)
//  U:  KV fp32 (K|V) / HH fp16 dbuf / finally E fp32 [44][132]
//  PK: SE-A / SE-B out_enc parks (cat cols 256:384 / 384:512), swizzled
struct Smem {
    _Float16 XH[PROWS * 256];                 // 24576 B
    __align__(16) char U[PROWS * 128 * 4];    // 24576 B
    _Float16 PK[2][PROWS * 128];              // 24576 B
    float LNp[PROWS * 4], LNq[PROWS * 4];     // 1536 B (LNp reused as Sd)
    float Sx[MROWS * 4];                      // 704 B
};

// Forensics (R0-R10 this session + prev):
//  - runtime-indexed acc arrays -> stack. Never.
//  - R2: forcing 3 waves/SIMD via launch_bounds -> ~350MB spill, 2x slower.
//    Occupancy lever DEAD (kernel needs ~256 regs/wave). Delete work instead.
//  - R3: tok@qkv folded, LN inlined, HH dbuf. R5/R6: head loop form
//    irrelevant; the cat HBM round-trip was the cost -> R7 fused tail via
//    LDS parks (1285.6us). R10 split emb tail (1273.8us, best).
//  - SE-merge line is DEAD: R4/R8/R9 all absmax-FAIL; second wave-split bug
//    never found statically. Do not reattempt blind.
//  - R10 diagnostic: ~119MB WRITE residual is NOT the emb accumulator
//    (halving it changed nothing) and at 1.5% HBM util it is COSMETIC.
//    Stop chasing scratch; the kernel is a latency-bound barrier chain.
//  - R11 (this): T5 setprio around MFMA clusters (2 independent chains/CU =
//    the attn-positive regime, m191) + pe_emb expf-table hoist. Both
//    bit-identical numerics.
struct Args {
    const float *q_t, *skelA, *skelB;
    const float *qe_o_b, *qe_ln_g, *qe_ln_b, *qe_m1_b, *qe_m2_b;
    const float *se_o_b, *se_ln_g, *se_ln_b, *se_m1_b, *se_m2_b;
    const float *fqe, *fse;       // folded tok@qkv weights + bias
    const float *P;               // [22][128] pe@embW+emb_b
    const float *del_W, *del_b, *quat_mean, *quat_std;
    const _Float16 *W;
    float *out;
};

// XOR-chunk swizzle within a row: chunk = c>>3 (8 fp16 = 16B), chunk' = chunk ^ (r&7).
__device__ __forceinline__ int swz(int r, int c) {
    return (((c >> 3) ^ (r & 7)) << 3) | (c & 7);
}

// acc[i][rt] += A[rt*16.., kA] * B[n=(w+4i)*16.., koff+kA]
// A single fp16 plane (LDS, swizzled); B dual fp16 planes (global) -> 2 MFMAs.
// setprio(1) around the MFMA cluster: with 2 independent block chains per CU
// (different phases), the MFMA-entering chain wins CU arbitration (T5/m191).
template<int NI, int KSTEPS, int LDA>
__device__ __forceinline__ void mfma_gemm(f4 (&acc)[NI][NRT],
        const _Float16 *AH,
        const _Float16 *BH, const _Float16 *BL,
        int wK, int koff, int w, int l) {
    const int m = l & 15, q = l >> 4;
#pragma unroll 1
    for (int s = 0; s < KSTEPS; s++) {
        const int ka = s * 32 + q * 8;
        h8 a[NRT];
#pragma unroll
        for (int rt = 0; rt < NRT; rt++) {
            int r = rt * 16 + m;
            a[rt] = *(const h8 *)(AH + r * LDA + (((ka >> 3) ^ (r & 7)) << 3));
        }
        __builtin_amdgcn_s_setprio(1);
#pragma unroll
        for (int i = 0; i < NI; i++) {
            int n = (w + 4 * i) * 16 + m;
            int boff = n * wK + koff + ka;
            h8 bh = *(const h8 *)(BH + boff);
            h8 bl = *(const h8 *)(BL + boff);
#pragma unroll
            for (int rt = 0; rt < NRT; rt++) {
                acc[i][rt] = __builtin_amdgcn_mfma_f32_16x16x32_f16(a[rt], bh, acc[i][rt], 0, 0, 0);
                acc[i][rt] = __builtin_amdgcn_mfma_f32_16x16x32_f16(a[rt], bl, acc[i][rt], 0, 0, 0);
            }
        }
        __builtin_amdgcn_s_setprio(0);
    }
}

// attention: unit = (head,row[,half]); each unit covers 16 head-dims.
// SE (HD=32): lane pairs (u^1) combine QK partial dots via shfl_xor.
template<int NH, int HD>
__device__ __forceinline__ void attention(Smem &sm, int t) {
    constexpr int SPL = HD / 16;
    if (t < NH * MROWS * SPL) {
        const int half = t & (SPL - 1);
        const int ur = t / SPL;
        const int hh = ur / MROWS;
        const int rr = ur - hh * MROWS;
        const int jb = (rr >= NJ) ? NJ : 0;
        const float *KF = (const float *)sm.U;           // [48][64]
        const float *VF = KF + PROWS * 64;               // [48][64]
        const int c0 = 64 + hh * HD + half * 16;         // q col base in X
        float qv[16];
#pragma unroll
        for (int g = 0; g < 2; g++) {
            h8 qh = *(const h8 *)(sm.XH + rr * 256 + swz(rr, c0 + g * 8));
#pragma unroll
            for (int d = 0; d < 8; d++) qv[g * 8 + d] = (float)qh[d];
        }
        float s[NJ];
        float mx = -1e30f;
#pragma unroll
        for (int j = 0; j < NJ; j++) {
            const float *kp = KF + (jb + j) * 64 + hh * HD + half * 16;
            float acc = 0.f;
#pragma unroll
            for (int d = 0; d < 16; d += 4) {
                float4 v = *(const float4 *)(kp + d);
                acc += qv[d] * v.x + qv[d + 1] * v.y + qv[d + 2] * v.z + qv[d + 3] * v.w;
            }
            if constexpr (SPL == 2) acc += __shfl_xor(acc, 1);
            s[j] = acc * 0.125f;        // scale = 64^-0.5 for both encoders
            mx = fmaxf(mx, s[j]);
        }
        float sum = 0.f;
#pragma unroll
        for (int j = 0; j < NJ; j++) { s[j] = __expf(s[j] - mx); sum += s[j]; }
        float inv = 1.f / sum;
        float o[16];
#pragma unroll
        for (int d = 0; d < 16; d++) o[d] = 0.f;
#pragma unroll
        for (int j = 0; j < NJ; j++) {
            float p = s[j] * inv;
            const float *vp = VF + (jb + j) * 64 + hh * HD + half * 16;
#pragma unroll
            for (int d = 0; d < 16; d += 4) {
                float4 v = *(const float4 *)(vp + d);
                o[d] = fmaf(p, v.x, o[d]);       o[d + 1] = fmaf(p, v.y, o[d + 1]);
                o[d + 2] = fmaf(p, v.z, o[d + 2]); o[d + 3] = fmaf(p, v.w, o[d + 3]);
            }
        }
        const int cw = hh * HD + half * 16;              // AO col base
#pragma unroll
        for (int g = 0; g < 2; g++) {
            h8 oh;
#pragma unroll
            for (int d = 0; d < 8; d++) oh[d] = (_Float16)o[g * 8 + d];
            *(h8 *)(sm.XH + rr * 256 + swz(rr, cw + g * 8)) = oh;
        }
    }
}

template<int D, int NH, int TK>
__device__ __forceinline__ void encode(Smem &sm, const float *__restrict__ xg,
        const float *__restrict__ F,       // W'[TK][192] then b'[192]
        const float *__restrict__ oB,
        const float *__restrict__ lnG,  const float *__restrict__ lnB,
        const float *__restrict__ m1B,  const float *__restrict__ m2B,
        const _Float16 *__restrict__ Wo,
        const _Float16 *__restrict__ Wm1, const _Float16 *__restrict__ Wm2,
        _Float16 *__restrict__ outp, int outLDA, int t, int w, int l) {
    constexpr int NI = D / 64;
    constexpr int HID = 2 * D;
    const int m = l & 15, q = l >> 4;
    const float *FW = F, *Fb = F + TK * 192;

    if (t < MROWS * TK) sm.Sx[t] = xg[t];
    __syncthreads();                       // also guards prior encode's X/U reads
    // ---- folded tok@qkv (VALU): q -> X cols 64:128 fp16; k,v -> KV fp32.
    {
        float *KV = (float *)sm.U;
#pragma unroll
        for (int i = 0; i < 11; i++) {
            int r = w + 4 * i;
            float x0 = sm.Sx[r * TK + 0];
            float x1 = sm.Sx[r * TK + 1];
            float x2 = sm.Sx[r * TK + 2];
            float x3 = (TK == 4) ? sm.Sx[r * TK + 3] : 0.f;
#pragma unroll
            for (int kk = 0; kk < 3; kk++) {
                int c = kk * 64 + l;
                float acc = Fb[c];
                acc = fmaf(x0, FW[0 * 192 + c], acc);
                acc = fmaf(x1, FW[1 * 192 + c], acc);
                acc = fmaf(x2, FW[2 * 192 + c], acc);
                if (TK == 4) acc = fmaf(x3, FW[3 * 192 + c], acc);
                if (kk == 0)      sm.XH[r * 256 + swz(r, 64 + l)] = (_Float16)acc;
                else if (kk == 1) KV[r * 64 + l] = acc;                 // K
                else              KV[PROWS * 64 + r * 64 + l] = acc;    // V
            }
        }
    }
    __syncthreads();
    attention<NH, 64 / NH>(sm, t);
    __syncthreads();
    // ---- o GEMM: res = AO @ Wo + oB  (residual; also the MLP accumulator)
    f4 res[NI][NRT];
#pragma unroll
    for (int i = 0; i < NI; i++)
#pragma unroll
        for (int rt = 0; rt < NRT; rt++) res[i][rt] = (f4){0.f, 0.f, 0.f, 0.f};
    mfma_gemm<NI, 2, 256>(res, sm.XH, Wo, Wo + D * 64, 64, 0, w, l);
#pragma unroll
    for (int i = 0; i < NI; i++) {
        float b = oB[(w + 4 * i) * 16 + m];
#pragma unroll
        for (int rt = 0; rt < NRT; rt++)
#pragma unroll
            for (int e = 0; e < 4; e++) res[i][rt][e] += b;
    }
    // ---- LN partial stats (cross-wave via LDS)
#pragma unroll
    for (int rt = 0; rt < NRT; rt++)
#pragma unroll
        for (int e = 0; e < 4; e++) {
            int r = rt * 16 + q * 4 + e;
            float s1 = 0.f, s2 = 0.f;
#pragma unroll
            for (int i = 0; i < NI; i++) {
                float v = res[i][rt][e];
                s1 += v; s2 = fmaf(v, v, s2);
            }
#pragma unroll
            for (int off = 8; off > 0; off >>= 1) {
                s1 += __shfl_xor(s1, off);
                s2 += __shfl_xor(s2, off);
            }
            if (m == 0) { sm.LNp[r * 4 + w] = s1; sm.LNq[r * 4 + w] = s2; }
        }
    __syncthreads();
    // ---- hn -> X cols 0:D; LN final inlined per-thread
    {
        float gv[NI], bv[NI];
#pragma unroll
        for (int i = 0; i < NI; i++) {
            int c = (w + 4 * i) * 16 + m;
            gv[i] = lnG[c]; bv[i] = lnB[c];
        }
#pragma unroll
        for (int rt = 0; rt < NRT; rt++)
#pragma unroll
            for (int e = 0; e < 4; e++) {
                int r = rt * 16 + q * 4 + e;
                float s1 = sm.LNp[r * 4] + sm.LNp[r * 4 + 1] + sm.LNp[r * 4 + 2] + sm.LNp[r * 4 + 3];
                float s2 = sm.LNq[r * 4] + sm.LNq[r * 4 + 1] + sm.LNq[r * 4 + 2] + sm.LNq[r * 4 + 3];
                float mean = s1 * (1.f / D);
                float var = s2 * (1.f / D) - mean * mean;
                float rinv = rsqrtf(fmaxf(var, 0.f) + 1e-5f);
#pragma unroll
                for (int i = 0; i < NI; i++) {
                    int c = (w + 4 * i) * 16 + m;
                    float v = (res[i][rt][e] - mean) * rinv * gv[i] + bv[i];
                    sm.XH[r * 256 + swz(r, c)] = (_Float16)v;
                }
            }
    }
    __syncthreads();
    // ---- MLP: hid in 128-col blocks; HH double-buffered in U -> ONE barrier/cb.
#pragma unroll 1
    for (int cb = 0; cb < HID / 128; cb++) {
        f4 h1[2][NRT];
#pragma unroll
        for (int i = 0; i < 2; i++)
#pragma unroll
            for (int rt = 0; rt < NRT; rt++) h1[i][rt] = (f4){0.f, 0.f, 0.f, 0.f};
        mfma_gemm<2, D / 32, 256>(h1, sm.XH,
                                  Wm1 + cb * 128 * D, Wm1 + HID * D + cb * 128 * D, D, 0, w, l);
        _Float16 *HH = (_Float16 *)sm.U + (cb & 1) * (PROWS * 128);
#pragma unroll
        for (int i = 0; i < 2; i++) {
            int c = (w + 4 * i) * 16 + m;
            float b = m1B[cb * 128 + c];
#pragma unroll
            for (int rt = 0; rt < NRT; rt++)
#pragma unroll
                for (int e = 0; e < 4; e++) {
                    int r = rt * 16 + q * 4 + e;
                    HH[r * 128 + swz(r, c)] = (_Float16)fmaxf(h1[i][rt][e] + b, 0.f);
                }
        }
        __syncthreads();
        mfma_gemm<NI, 4, 128>(res, HH, Wm2, Wm2 + D * HID, HID, cb * 128, w, l);
    }
    // ---- out_enc = res + b2 -> swizzled LDS park (all 48 rows; pads are
    // finite and consumed only by discarded emb pad rows). Safe: park
    // targets' last readers (m1 of final cb) completed before that cb's
    // barrier; m2 reads U only. (R7-verified. R8 lesson: a park target must
    // never alias a buffer read after the last barrier.)
#pragma unroll
    for (int i = 0; i < NI; i++) {
        int c = (w + 4 * i) * 16 + m;
        float b = m2B[c];
#pragma unroll
        for (int rt = 0; rt < NRT; rt++)
#pragma unroll
            for (int e = 0; e < 4; e++) {
                int r = rt * 16 + q * 4 + e;
                outp[r * outLDA + swz(r, c)] = (_Float16)(res[i][rt][e] + b);
            }
    }
}

__global__ __launch_bounds__(256, 2) void fused_kernel(Args A) {
    __shared__ __align__(16) Smem sm;
    const int t = threadIdx.x, w = t >> 6, l = t & 63;
    const int m = l & 15, q = l >> 4;
    const int blk = blockIdx.x;

    // zero pad rows 44..47 of X (dead rows; keeps NaN-free fragments)
    for (int i = t; i < 4 * 256; i += 256) {
        int r = MROWS + (i >> 8), c = i & 255;
        sm.XH[r * 256 + c] = (_Float16)0.f;
    }

    const _Float16 *W = A.W;

    // SE encodes first (outs parked in PK); QE last (out stays in XH).
    encode<128, 2, 3>(sm, A.skelA + blk * MROWS * 3, A.fse,
                      A.se_o_b, A.se_ln_g, A.se_ln_b, A.se_m1_b, A.se_m2_b,
                      W + WOFF_SE_O, W + WOFF_SE_M1, W + WOFF_SE_M2,
                      sm.PK[0], 128, t, w, l);
    encode<128, 2, 3>(sm, A.skelB + blk * MROWS * 3, A.fse,
                      A.se_o_b, A.se_ln_g, A.se_ln_b, A.se_m1_b, A.se_m2_b,
                      W + WOFF_SE_O, W + WOFF_SE_M1, W + WOFF_SE_M2,
                      sm.PK[1], 128, t, w, l);
    encode<256, 4, 4>(sm, A.q_t + blk * MROWS * 4, A.fqe,
                      A.qe_o_b, A.qe_ln_g, A.qe_ln_b, A.qe_m1_b, A.qe_m2_b,
                      W + WOFF_QE_O, W + WOFF_QE_M1, W + WOFF_QE_M2,
                      sm.XH, 256, t, w, l);

    __syncthreads();   // QE out->XH visible; all U (HH) readers done
    // ---- emb = cat @ embW, K order 0:256 (XH) | 256:384 (PK0) | 384:512 (PK1)
    // — computed in TWO sequential NI=1 halves (n-tile w, then w+4), E write
    // retiring each half's 12 accumulators early. Per-element MFMA chain
    // identical to the R7 head.
    const _Float16 *We = W + WOFF_EMB;            // [128][512] hi
    const _Float16 *WeL = We + 128 * 512;         // lo
    float *E = (float *)sm.U;
#pragma unroll 1
    for (int ih = 0; ih < 2; ih++) {
        f4 emb[1][NRT];
#pragma unroll
        for (int rt = 0; rt < NRT; rt++) emb[0][rt] = (f4){0.f, 0.f, 0.f, 0.f};
        mfma_gemm<1, 8, 256>(emb, sm.XH,    We, WeL, 512, 0,   w + 4 * ih, l);
        mfma_gemm<1, 4, 128>(emb, sm.PK[0], We, WeL, 512, 256, w + 4 * ih, l);
        mfma_gemm<1, 4, 128>(emb, sm.PK[1], We, WeL, 512, 384, w + 4 * ih, l);
        // E = relu(sqrt(512)*emb + P[j]) -> U as f32 [44][132]. Safe: U's
        // last readers (QE m2 HH) drained by the barrier above; emb gemms
        // read XH/PK only.
        int c = (w + 4 * ih) * 16 + m;
#pragma unroll
        for (int rt = 0; rt < NRT; rt++)
#pragma unroll
            for (int e = 0; e < 4; e++) {
                int r = rt * 16 + q * 4 + e;
                if (r < MROWS) {
                    int j = (r >= NJ) ? r - NJ : r;
                    float v = fmaf(22.627416997969522f, emb[0][rt][e], A.P[j * 128 + c]);
                    E[r * 132 + c] = fmaxf(v, 0.f);
                }
            }
    }
    __syncthreads();
    // ---- del: 176 threads = 44 rows x 4 outputs (Sd aliases LNp, dead)
    float *Sd = sm.LNp;
    if (t < MROWS * 4) {
        int r = t >> 2, d = t & 3;
        float a2 = A.del_b[d];
        const float *Er = E + r * 132;
#pragma unroll 4
        for (int c4 = 0; c4 < 32; c4++) {
            float4 ev = *(const float4 *)(Er + c4 * 4);
            a2 = fmaf(ev.x, A.del_W[(c4 * 4 + 0) * 4 + d], a2);
            a2 = fmaf(ev.y, A.del_W[(c4 * 4 + 1) * 4 + d], a2);
            a2 = fmaf(ev.z, A.del_W[(c4 * 4 + 2) * 4 + d], a2);
            a2 = fmaf(ev.w, A.del_W[(c4 * 4 + 3) * 4 + d], a2);
        }
        int j = (r >= NJ) ? r - NJ : r;
        Sd[t] = fmaf(a2, A.quat_std[j * 4 + d], A.quat_mean[j * 4 + d]);
    }
    __syncthreads();
    if (t < MROWS * 4) {
        int r = t >> 2;
        float x0 = Sd[r * 4], x1 = Sd[r * 4 + 1];
        float x2 = Sd[r * 4 + 2], x3 = Sd[r * 4 + 3];
        float inv = 1.f / sqrtf(x0 * x0 + x1 * x1 + x2 * x2 + x3 * x3);
        A.out[((size_t)blk * MROWS + r) * 4 + (t & 3)] = Sd[t] * inv;
    }
}

// ---- setup: split+transpose all GEMM weights into [N][K] fp16 hi/lo planes ----
struct WDesc { const float *W; int K; int N; int off; };
struct SplitArgs { WDesc d[9]; _Float16 *out; };

__global__ void split_kernel(SplitArgs a) {
    WDesc d = a.d[blockIdx.y];
    int e = blockIdx.x * 256 + threadIdx.x;
    int tot = d.K * d.N;
    if (e < tot) {
        int n = e / d.K, k = e - n * d.K;
        float v = d.W[k * d.N + n];
        _Float16 h = (_Float16)v;
        a.out[d.off + e] = h;
        a.out[d.off + tot + e] = (_Float16)(v - (float)h);
    }
}

// ---- fold: W' = tokW @ qkvW (f32), b' = tokB @ qkvW + qkvB ----
struct FoldArgs {
    const float *qe_tokW, *qe_tokB, *qe_qkvW, *qe_qkvB;
    const float *se_tokW, *se_tokB, *se_qkvW, *se_qkvB;
    float *fqe, *fse;
};

__global__ void fold_kernel(FoldArgs a) {
    int c = threadIdx.x;               // 0..191
    if (blockIdx.x == 0) {
#pragma unroll
        for (int kk = 0; kk < 4; kk++) {
            float acc = 0.f;
            for (int k = 0; k < 64; k++)
                acc = fmaf(a.qe_tokW[kk * 64 + k], a.qe_qkvW[k * 192 + c], acc);
            a.fqe[kk * 192 + c] = acc;
        }
        float acc = a.qe_qkvB[c];
        for (int k = 0; k < 64; k++)
            acc = fmaf(a.qe_tokB[k], a.qe_qkvW[k * 192 + c], acc);
        a.fqe[4 * 192 + c] = acc;
    } else {
#pragma unroll
        for (int kk = 0; kk < 3; kk++) {
            float acc = 0.f;
            for (int k = 0; k < 64; k++)
                acc = fmaf(a.se_tokW[kk * 64 + k], a.se_qkvW[k * 192 + c], acc);
            a.fse[kk * 192 + c] = acc;
        }
        float acc = a.se_qkvB[c];
        for (int k = 0; k < 64; k++)
            acc = fmaf(a.se_tokB[k], a.se_qkvW[k * 192 + c], acc);
        a.fse[3 * 192 + c] = acc;
    }
}

// P[r][c] = (pe @ emb_W)[r][c] + emb_b[c]
// div[i] = exp(i*k) is thread/row-invariant -> computed once into LDS
// (identical expf op & input as before -> bit-identical P).
__global__ void pe_emb_kernel(const float *__restrict__ emb_W,
                              const float *__restrict__ emb_b, float *P) {
    __shared__ float div[256];
    int r = blockIdx.x;        // 0..21
    int c = threadIdx.x;       // 0..127
    const float k = -2.f * logf(10000.f) / 512.f;
    for (int i = c; i < 256; i += 128) div[i] = expf((float)i * k);
    __syncthreads();
    float acc = emb_b[c];
    for (int i = 0; i < 256; i++) {
        float ang = (float)r * div[i];
        acc = fmaf(sinf(ang), emb_W[(2 * i) * 128 + c], acc);
        acc = fmaf(cosf(ang), emb_W[(2 * i + 1) * 128 + c], acc);
    }
    P[r * 128 + c] = acc;
}

extern "C" void kernel_launch(void *const *d_in, const int *in_sizes, int n_in,
                              void *d_out, int out_size, void *d_ws, size_t ws_size,
                              hipStream_t stream) {
    const float **in = (const float **)d_in;
    float *dwf = (float *)d_ws;
    float *P   = dwf;                  // 2816 floats
    float *FQE = dwf + 2816;           // 960 floats
    float *FSE = dwf + 3776;           // 768 floats
    _Float16 *W = (_Float16 *)(dwf + 4544);

    Args A;
    A.q_t = in[0]; A.skelA = in[1]; A.skelB = in[2];
    A.qe_o_b = in[10]; A.qe_ln_g = in[11]; A.qe_ln_b = in[12];
    A.qe_m1_b = in[14]; A.qe_m2_b = in[16];
    A.se_o_b = in[22]; A.se_ln_g = in[23]; A.se_ln_b = in[24];
    A.se_m1_b = in[26]; A.se_m2_b = in[28];
    A.fqe = FQE; A.fse = FSE;
    A.P = P;
    A.del_W = in[31]; A.del_b = in[32];
    A.quat_mean = in[3]; A.quat_std = in[4];
    A.W = W; A.out = (float *)d_out;

    SplitArgs sa;
    sa.d[0] = { in[7],  64, 192, WOFF_QE_QKV };
    sa.d[1] = { in[9],  64, 256, WOFF_QE_O };
    sa.d[2] = { in[13], 256, 512, WOFF_QE_M1 };
    sa.d[3] = { in[15], 512, 256, WOFF_QE_M2 };
    sa.d[4] = { in[19], 64, 192, WOFF_SE_QKV };
    sa.d[5] = { in[21], 64, 128, WOFF_SE_O };
    sa.d[6] = { in[25], 128, 256, WOFF_SE_M1 };
    sa.d[7] = { in[27], 256, 128, WOFF_SE_M2 };
    sa.d[8] = { in[29], 512, 128, WOFF_EMB };
    sa.out = W;

    FoldArgs fa;
    fa.qe_tokW = in[5];  fa.qe_tokB = in[6];  fa.qe_qkvW = in[7];  fa.qe_qkvB = in[8];
    fa.se_tokW = in[17]; fa.se_tokB = in[18]; fa.se_qkvW = in[19]; fa.se_qkvB = in[20];
    fa.fqe = FQE; fa.fse = FSE;

    int n_items = in_sizes[0] / (NJ * 4);
    int blocks = n_items / 2;          // 2 items per block

    split_kernel<<<dim3(512, 9), 256, 0, stream>>>(sa);
    fold_kernel<<<2, 192, 0, stream>>>(fa);
    pe_emb_kernel<<<NJ, 128, 0, stream>>>(in[29], in[30], P);
    fused_kernel<<<blocks, 256, 0, stream>>>(A);
}

// Round 13
// 1269.389 us; speedup vs baseline: 1.0129x; 1.0129x over previous
//
#include <hip/hip_runtime.h>
#include <hip/hip_bf16.h>
#include <math.h>

#define NJ 22
#define MROWS 44          // 2 items x 22 joints per block
#define PROWS 48          // padded rows (3 row-tiles of 16)
#define NRT 3

typedef float f4 __attribute__((ext_vector_type(4)));
typedef _Float16 h8 __attribute__((ext_vector_type(8)));

// ---- d_ws layout (floats) ----
// P[2816] | FQE[960] (W'[4][192], b'[192]) | FSE[768] (W'[3][192], b'[192]) |
// fp16 weight planes (hi [N][K], then lo [N][K]) at half-offsets below
#define WOFF_QE_QKV 0        // (unused by fused; kept in split for layout)
#define WOFF_QE_O   24576    // K=64  N=256
#define WOFF_QE_M1  57344    // K=256 N=512
#define WOFF_QE_M2  319488   // K=512 N=256
#define WOFF_SE_QKV 581632
#define WOFF_SE_O   606208   // K=64  N=128
#define WOFF_SE_M1  622592   // K=128 N=256
#define WOFF_SE_M2  688128   // K=256 N=128
#define WOFF_EMB    753664   // K=512 N=128
#define W_TOTAL     884736   // halfs (incl emb hi+lo)

// LDS (~76.5K/block -> 2 blocks/CU):
//  XH: X fp16 plane [48][256] swizzled; finally QE's out_enc (cat cols 0:256)
//  U:  KV fp32 (K|V) / HH fp16 dbuf / finally E fp32 [44][132]
//  PK: SE-A / SE-B out_enc parks (cat cols 256:384 / 384:512), swizzled
struct Smem {
    _Float16 XH[PROWS * 256];                 // 24576 B
    __align__(16) char U[PROWS * 128 * 4];    // 24576 B
    _Float16 PK[2][PROWS * 128];              // 24576 B
    float LNp[PROWS * 4], LNq[PROWS * 4];     // 1536 B (LNp reused as Sd)
    float Sx[MROWS * 4];                      // 704 B
};

// Forensics (R0-R12 this session + prev) — FINAL CONFIGURATION:
//  - runtime-indexed acc arrays -> stack. Never.
//  - R2: forcing 3 waves/SIMD via launch_bounds -> ~350MB spill, 2x slower.
//    Occupancy lever DEAD (kernel needs ~256 regs/wave + 76.5KB LDS; both
//    constraints bind at 2 blocks/CU).
//  - R3: tok@qkv folded, LN inlined, HH dbuf. R5/R6 A/B: head loop form
//    irrelevant; the cat HBM round-trip was the cost -> R7 fused tail via
//    LDS parks (1285.6us). R10 split emb tail (1273.8us, best).
//  - SE-merge line DEAD: R4/R8/R9 all absmax-FAIL (R8's PK-alias race found;
//    a second wave-split bug was not findable statically).
//  - R10 diagnostic: ~119MB WRITE residual is NOT the emb accumulator and at
//    ~1.5% HBM util is COSMETIC.
//  - R11 A/B: setprio NEUTRAL (fused 1185->1186) -> reverted here. pe_emb
//    expf-table kept (strictly less work, bit-identical P).
//  - R12: bench infra failure ("container failed twice"); this is an
//    unmodified resubmission.
//  - Kernel is latency-bound at its structural floor: ~20 barriers/block,
//    each guarding a real LDS transpose dependency; 2 independent chains/CU.
struct Args {
    const float *q_t, *skelA, *skelB;
    const float *qe_o_b, *qe_ln_g, *qe_ln_b, *qe_m1_b, *qe_m2_b;
    const float *se_o_b, *se_ln_g, *se_ln_b, *se_m1_b, *se_m2_b;
    const float *fqe, *fse;       // folded tok@qkv weights + bias
    const float *P;               // [22][128] pe@embW+emb_b
    const float *del_W, *del_b, *quat_mean, *quat_std;
    const _Float16 *W;
    float *out;
};

// XOR-chunk swizzle within a row: chunk = c>>3 (8 fp16 = 16B), chunk' = chunk ^ (r&7).
__device__ __forceinline__ int swz(int r, int c) {
    return (((c >> 3) ^ (r & 7)) << 3) | (c & 7);
}

// acc[i][rt] += A[rt*16.., kA] * B[n=(w+4i)*16.., koff+kA]
// A single fp16 plane (LDS, swizzled); B dual fp16 planes (global) -> 2 MFMAs.
template<int NI, int KSTEPS, int LDA>
__device__ __forceinline__ void mfma_gemm(f4 (&acc)[NI][NRT],
        const _Float16 *AH,
        const _Float16 *BH, const _Float16 *BL,
        int wK, int koff, int w, int l) {
    const int m = l & 15, q = l >> 4;
#pragma unroll 1
    for (int s = 0; s < KSTEPS; s++) {
        const int ka = s * 32 + q * 8;
        h8 a[NRT];
#pragma unroll
        for (int rt = 0; rt < NRT; rt++) {
            int r = rt * 16 + m;
            a[rt] = *(const h8 *)(AH + r * LDA + (((ka >> 3) ^ (r & 7)) << 3));
        }
#pragma unroll
        for (int i = 0; i < NI; i++) {
            int n = (w + 4 * i) * 16 + m;
            int boff = n * wK + koff + ka;
            h8 bh = *(const h8 *)(BH + boff);
            h8 bl = *(const h8 *)(BL + boff);
#pragma unroll
            for (int rt = 0; rt < NRT; rt++) {
                acc[i][rt] = __builtin_amdgcn_mfma_f32_16x16x32_f16(a[rt], bh, acc[i][rt], 0, 0, 0);
                acc[i][rt] = __builtin_amdgcn_mfma_f32_16x16x32_f16(a[rt], bl, acc[i][rt], 0, 0, 0);
            }
        }
    }
}

// attention: unit = (head,row[,half]); each unit covers 16 head-dims.
// SE (HD=32): lane pairs (u^1) combine QK partial dots via shfl_xor.
template<int NH, int HD>
__device__ __forceinline__ void attention(Smem &sm, int t) {
    constexpr int SPL = HD / 16;
    if (t < NH * MROWS * SPL) {
        const int half = t & (SPL - 1);
        const int ur = t / SPL;
        const int hh = ur / MROWS;
        const int rr = ur - hh * MROWS;
        const int jb = (rr >= NJ) ? NJ : 0;
        const float *KF = (const float *)sm.U;           // [48][64]
        const float *VF = KF + PROWS * 64;               // [48][64]
        const int c0 = 64 + hh * HD + half * 16;         // q col base in X
        float qv[16];
#pragma unroll
        for (int g = 0; g < 2; g++) {
            h8 qh = *(const h8 *)(sm.XH + rr * 256 + swz(rr, c0 + g * 8));
#pragma unroll
            for (int d = 0; d < 8; d++) qv[g * 8 + d] = (float)qh[d];
        }
        float s[NJ];
        float mx = -1e30f;
#pragma unroll
        for (int j = 0; j < NJ; j++) {
            const float *kp = KF + (jb + j) * 64 + hh * HD + half * 16;
            float acc = 0.f;
#pragma unroll
            for (int d = 0; d < 16; d += 4) {
                float4 v = *(const float4 *)(kp + d);
                acc += qv[d] * v.x + qv[d + 1] * v.y + qv[d + 2] * v.z + qv[d + 3] * v.w;
            }
            if constexpr (SPL == 2) acc += __shfl_xor(acc, 1);
            s[j] = acc * 0.125f;        // scale = 64^-0.5 for both encoders
            mx = fmaxf(mx, s[j]);
        }
        float sum = 0.f;
#pragma unroll
        for (int j = 0; j < NJ; j++) { s[j] = __expf(s[j] - mx); sum += s[j]; }
        float inv = 1.f / sum;
        float o[16];
#pragma unroll
        for (int d = 0; d < 16; d++) o[d] = 0.f;
#pragma unroll
        for (int j = 0; j < NJ; j++) {
            float p = s[j] * inv;
            const float *vp = VF + (jb + j) * 64 + hh * HD + half * 16;
#pragma unroll
            for (int d = 0; d < 16; d += 4) {
                float4 v = *(const float4 *)(vp + d);
                o[d] = fmaf(p, v.x, o[d]);       o[d + 1] = fmaf(p, v.y, o[d + 1]);
                o[d + 2] = fmaf(p, v.z, o[d + 2]); o[d + 3] = fmaf(p, v.w, o[d + 3]);
            }
        }
        const int cw = hh * HD + half * 16;              // AO col base
#pragma unroll
        for (int g = 0; g < 2; g++) {
            h8 oh;
#pragma unroll
            for (int d = 0; d < 8; d++) oh[d] = (_Float16)o[g * 8 + d];
            *(h8 *)(sm.XH + rr * 256 + swz(rr, cw + g * 8)) = oh;
        }
    }
}

template<int D, int NH, int TK>
__device__ __forceinline__ void encode(Smem &sm, const float *__restrict__ xg,
        const float *__restrict__ F,       // W'[TK][192] then b'[192]
        const float *__restrict__ oB,
        const float *__restrict__ lnG,  const float *__restrict__ lnB,
        const float *__restrict__ m1B,  const float *__restrict__ m2B,
        const _Float16 *__restrict__ Wo,
        const _Float16 *__restrict__ Wm1, const _Float16 *__restrict__ Wm2,
        _Float16 *__restrict__ outp, int outLDA, int t, int w, int l) {
    constexpr int NI = D / 64;
    constexpr int HID = 2 * D;
    const int m = l & 15, q = l >> 4;
    const float *FW = F, *Fb = F + TK * 192;

    if (t < MROWS * TK) sm.Sx[t] = xg[t];
    __syncthreads();                       // also guards prior encode's X/U reads
    // ---- folded tok@qkv (VALU): q -> X cols 64:128 fp16; k,v -> KV fp32.
    {
        float *KV = (float *)sm.U;
#pragma unroll
        for (int i = 0; i < 11; i++) {
            int r = w + 4 * i;
            float x0 = sm.Sx[r * TK + 0];
            float x1 = sm.Sx[r * TK + 1];
            float x2 = sm.Sx[r * TK + 2];
            float x3 = (TK == 4) ? sm.Sx[r * TK + 3] : 0.f;
#pragma unroll
            for (int kk = 0; kk < 3; kk++) {
                int c = kk * 64 + l;
                float acc = Fb[c];
                acc = fmaf(x0, FW[0 * 192 + c], acc);
                acc = fmaf(x1, FW[1 * 192 + c], acc);
                acc = fmaf(x2, FW[2 * 192 + c], acc);
                if (TK == 4) acc = fmaf(x3, FW[3 * 192 + c], acc);
                if (kk == 0)      sm.XH[r * 256 + swz(r, 64 + l)] = (_Float16)acc;
                else if (kk == 1) KV[r * 64 + l] = acc;                 // K
                else              KV[PROWS * 64 + r * 64 + l] = acc;    // V
            }
        }
    }
    __syncthreads();
    attention<NH, 64 / NH>(sm, t);
    __syncthreads();
    // ---- o GEMM: res = AO @ Wo + oB  (residual; also the MLP accumulator)
    f4 res[NI][NRT];
#pragma unroll
    for (int i = 0; i < NI; i++)
#pragma unroll
        for (int rt = 0; rt < NRT; rt++) res[i][rt] = (f4){0.f, 0.f, 0.f, 0.f};
    mfma_gemm<NI, 2, 256>(res, sm.XH, Wo, Wo + D * 64, 64, 0, w, l);
#pragma unroll
    for (int i = 0; i < NI; i++) {
        float b = oB[(w + 4 * i) * 16 + m];
#pragma unroll
        for (int rt = 0; rt < NRT; rt++)
#pragma unroll
            for (int e = 0; e < 4; e++) res[i][rt][e] += b;
    }
    // ---- LN partial stats (cross-wave via LDS)
#pragma unroll
    for (int rt = 0; rt < NRT; rt++)
#pragma unroll
        for (int e = 0; e < 4; e++) {
            int r = rt * 16 + q * 4 + e;
            float s1 = 0.f, s2 = 0.f;
#pragma unroll
            for (int i = 0; i < NI; i++) {
                float v = res[i][rt][e];
                s1 += v; s2 = fmaf(v, v, s2);
            }
#pragma unroll
            for (int off = 8; off > 0; off >>= 1) {
                s1 += __shfl_xor(s1, off);
                s2 += __shfl_xor(s2, off);
            }
            if (m == 0) { sm.LNp[r * 4 + w] = s1; sm.LNq[r * 4 + w] = s2; }
        }
    __syncthreads();
    // ---- hn -> X cols 0:D; LN final inlined per-thread
    {
        float gv[NI], bv[NI];
#pragma unroll
        for (int i = 0; i < NI; i++) {
            int c = (w + 4 * i) * 16 + m;
            gv[i] = lnG[c]; bv[i] = lnB[c];
        }
#pragma unroll
        for (int rt = 0; rt < NRT; rt++)
#pragma unroll
            for (int e = 0; e < 4; e++) {
                int r = rt * 16 + q * 4 + e;
                float s1 = sm.LNp[r * 4] + sm.LNp[r * 4 + 1] + sm.LNp[r * 4 + 2] + sm.LNp[r * 4 + 3];
                float s2 = sm.LNq[r * 4] + sm.LNq[r * 4 + 1] + sm.LNq[r * 4 + 2] + sm.LNq[r * 4 + 3];
                float mean = s1 * (1.f / D);
                float var = s2 * (1.f / D) - mean * mean;
                float rinv = rsqrtf(fmaxf(var, 0.f) + 1e-5f);
#pragma unroll
                for (int i = 0; i < NI; i++) {
                    int c = (w + 4 * i) * 16 + m;
                    float v = (res[i][rt][e] - mean) * rinv * gv[i] + bv[i];
                    sm.XH[r * 256 + swz(r, c)] = (_Float16)v;
                }
            }
    }
    __syncthreads();
    // ---- MLP: hid in 128-col blocks; HH double-buffered in U -> ONE barrier/cb.
#pragma unroll 1
    for (int cb = 0; cb < HID / 128; cb++) {
        f4 h1[2][NRT];
#pragma unroll
        for (int i = 0; i < 2; i++)
#pragma unroll
            for (int rt = 0; rt < NRT; rt++) h1[i][rt] = (f4){0.f, 0.f, 0.f, 0.f};
        mfma_gemm<2, D / 32, 256>(h1, sm.XH,
                                  Wm1 + cb * 128 * D, Wm1 + HID * D + cb * 128 * D, D, 0, w, l);
        _Float16 *HH = (_Float16 *)sm.U + (cb & 1) * (PROWS * 128);
#pragma unroll
        for (int i = 0; i < 2; i++) {
            int c = (w + 4 * i) * 16 + m;
            float b = m1B[cb * 128 + c];
#pragma unroll
            for (int rt = 0; rt < NRT; rt++)
#pragma unroll
                for (int e = 0; e < 4; e++) {
                    int r = rt * 16 + q * 4 + e;
                    HH[r * 128 + swz(r, c)] = (_Float16)fmaxf(h1[i][rt][e] + b, 0.f);
                }
        }
        __syncthreads();
        mfma_gemm<NI, 4, 128>(res, HH, Wm2, Wm2 + D * HID, HID, cb * 128, w, l);
    }
    // ---- out_enc = res + b2 -> swizzled LDS park (all 48 rows; pads are
    // finite and consumed only by discarded emb pad rows). Safe: park
    // targets' last readers (m1 of final cb) completed before that cb's
    // barrier; m2 reads U only. (R7-verified. R8 lesson: a park target must
    // never alias a buffer read after the last barrier.)
#pragma unroll
    for (int i = 0; i < NI; i++) {
        int c = (w + 4 * i) * 16 + m;
        float b = m2B[c];
#pragma unroll
        for (int rt = 0; rt < NRT; rt++)
#pragma unroll
            for (int e = 0; e < 4; e++) {
                int r = rt * 16 + q * 4 + e;
                outp[r * outLDA + swz(r, c)] = (_Float16)(res[i][rt][e] + b);
            }
    }
}

__global__ __launch_bounds__(256, 2) void fused_kernel(Args A) {
    __shared__ __align__(16) Smem sm;
    const int t = threadIdx.x, w = t >> 6, l = t & 63;
    const int m = l & 15, q = l >> 4;
    const int blk = blockIdx.x;

    // zero pad rows 44..47 of X (dead rows; keeps NaN-free fragments)
    for (int i = t; i < 4 * 256; i += 256) {
        int r = MROWS + (i >> 8), c = i & 255;
        sm.XH[r * 256 + c] = (_Float16)0.f;
    }

    const _Float16 *W = A.W;

    // SE encodes first (outs parked in PK); QE last (out stays in XH).
    encode<128, 2, 3>(sm, A.skelA + blk * MROWS * 3, A.fse,
                      A.se_o_b, A.se_ln_g, A.se_ln_b, A.se_m1_b, A.se_m2_b,
                      W + WOFF_SE_O, W + WOFF_SE_M1, W + WOFF_SE_M2,
                      sm.PK[0], 128, t, w, l);
    encode<128, 2, 3>(sm, A.skelB + blk * MROWS * 3, A.fse,
                      A.se_o_b, A.se_ln_g, A.se_ln_b, A.se_m1_b, A.se_m2_b,
                      W + WOFF_SE_O, W + WOFF_SE_M1, W + WOFF_SE_M2,
                      sm.PK[1], 128, t, w, l);
    encode<256, 4, 4>(sm, A.q_t + blk * MROWS * 4, A.fqe,
                      A.qe_o_b, A.qe_ln_g, A.qe_ln_b, A.qe_m1_b, A.qe_m2_b,
                      W + WOFF_QE_O, W + WOFF_QE_M1, W + WOFF_QE_M2,
                      sm.XH, 256, t, w, l);

    __syncthreads();   // QE out->XH visible; all U (HH) readers done
    // ---- emb = cat @ embW, K order 0:256 (XH) | 256:384 (PK0) | 384:512 (PK1)
    // — computed in TWO sequential NI=1 halves (n-tile w, then w+4), E write
    // retiring each half's 12 accumulators early. Per-element MFMA chain
    // identical to the R7 head.
    const _Float16 *We = W + WOFF_EMB;            // [128][512] hi
    const _Float16 *WeL = We + 128 * 512;         // lo
    float *E = (float *)sm.U;
#pragma unroll 1
    for (int ih = 0; ih < 2; ih++) {
        f4 emb[1][NRT];
#pragma unroll
        for (int rt = 0; rt < NRT; rt++) emb[0][rt] = (f4){0.f, 0.f, 0.f, 0.f};
        mfma_gemm<1, 8, 256>(emb, sm.XH,    We, WeL, 512, 0,   w + 4 * ih, l);
        mfma_gemm<1, 4, 128>(emb, sm.PK[0], We, WeL, 512, 256, w + 4 * ih, l);
        mfma_gemm<1, 4, 128>(emb, sm.PK[1], We, WeL, 512, 384, w + 4 * ih, l);
        // E = relu(sqrt(512)*emb + P[j]) -> U as f32 [44][132]. Safe: U's
        // last readers (QE m2 HH) drained by the barrier above; emb gemms
        // read XH/PK only.
        int c = (w + 4 * ih) * 16 + m;
#pragma unroll
        for (int rt = 0; rt < NRT; rt++)
#pragma unroll
            for (int e = 0; e < 4; e++) {
                int r = rt * 16 + q * 4 + e;
                if (r < MROWS) {
                    int j = (r >= NJ) ? r - NJ : r;
                    float v = fmaf(22.627416997969522f, emb[0][rt][e], A.P[j * 128 + c]);
                    E[r * 132 + c] = fmaxf(v, 0.f);
                }
            }
    }
    __syncthreads();
    // ---- del: 176 threads = 44 rows x 4 outputs (Sd aliases LNp, dead)
    float *Sd = sm.LNp;
    if (t < MROWS * 4) {
        int r = t >> 2, d = t & 3;
        float a2 = A.del_b[d];
        const float *Er = E + r * 132;
#pragma unroll 4
        for (int c4 = 0; c4 < 32; c4++) {
            float4 ev = *(const float4 *)(Er + c4 * 4);
            a2 = fmaf(ev.x, A.del_W[(c4 * 4 + 0) * 4 + d], a2);
            a2 = fmaf(ev.y, A.del_W[(c4 * 4 + 1) * 4 + d], a2);
            a2 = fmaf(ev.z, A.del_W[(c4 * 4 + 2) * 4 + d], a2);
            a2 = fmaf(ev.w, A.del_W[(c4 * 4 + 3) * 4 + d], a2);
        }
        int j = (r >= NJ) ? r - NJ : r;
        Sd[t] = fmaf(a2, A.quat_std[j * 4 + d], A.quat_mean[j * 4 + d]);
    }
    __syncthreads();
    if (t < MROWS * 4) {
        int r = t >> 2;
        float x0 = Sd[r * 4], x1 = Sd[r * 4 + 1];
        float x2 = Sd[r * 4 + 2], x3 = Sd[r * 4 + 3];
        float inv = 1.f / sqrtf(x0 * x0 + x1 * x1 + x2 * x2 + x3 * x3);
        A.out[((size_t)blk * MROWS + r) * 4 + (t & 3)] = Sd[t] * inv;
    }
}

// ---- setup: split+transpose all GEMM weights into [N][K] fp16 hi/lo planes ----
struct WDesc { const float *W; int K; int N; int off; };
struct SplitArgs { WDesc d[9]; _Float16 *out; };

__global__ void split_kernel(SplitArgs a) {
    WDesc d = a.d[blockIdx.y];
    int e = blockIdx.x * 256 + threadIdx.x;
    int tot = d.K * d.N;
    if (e < tot) {
        int n = e / d.K, k = e - n * d.K;
        float v = d.W[k * d.N + n];
        _Float16 h = (_Float16)v;
        a.out[d.off + e] = h;
        a.out[d.off + tot + e] = (_Float16)(v - (float)h);
    }
}

// ---- fold: W' = tokW @ qkvW (f32), b' = tokB @ qkvW + qkvB ----
struct FoldArgs {
    const float *qe_tokW, *qe_tokB, *qe_qkvW, *qe_qkvB;
    const float *se_tokW, *se_tokB, *se_qkvW, *se_qkvB;
    float *fqe, *fse;
};

__global__ void fold_kernel(FoldArgs a) {
    int c = threadIdx.x;               // 0..191
    if (blockIdx.x == 0) {
#pragma unroll
        for (int kk = 0; kk < 4; kk++) {
            float acc = 0.f;
            for (int k = 0; k < 64; k++)
                acc = fmaf(a.qe_tokW[kk * 64 + k], a.qe_qkvW[k * 192 + c], acc);
            a.fqe[kk * 192 + c] = acc;
        }
        float acc = a.qe_qkvB[c];
        for (int k = 0; k < 64; k++)
            acc = fmaf(a.qe_tokB[k], a.qe_qkvW[k * 192 + c], acc);
        a.fqe[4 * 192 + c] = acc;
    } else {
#pragma unroll
        for (int kk = 0; kk < 3; kk++) {
            float acc = 0.f;
            for (int k = 0; k < 64; k++)
                acc = fmaf(a.se_tokW[kk * 64 + k], a.se_qkvW[k * 192 + c], acc);
            a.fse[kk * 192 + c] = acc;
        }
        float acc = a.se_qkvB[c];
        for (int k = 0; k < 64; k++)
            acc = fmaf(a.se_tokB[k], a.se_qkvW[k * 192 + c], acc);
        a.fse[3 * 192 + c] = acc;
    }
}

// P[r][c] = (pe @ emb_W)[r][c] + emb_b[c]
// div[i] = exp(i*k) is thread/row-invariant -> computed once into LDS
// (identical expf op & input as before -> bit-identical P).
__global__ void pe_emb_kernel(const float *__restrict__ emb_W,
                              const float *__restrict__ emb_b, float *P) {
    __shared__ float div[256];
    int r = blockIdx.x;        // 0..21
    int c = threadIdx.x;       // 0..127
    const float k = -2.f * logf(10000.f) / 512.f;
    for (int i = c; i < 256; i += 128) div[i] = expf((float)i * k);
    __syncthreads();
    float acc = emb_b[c];
    for (int i = 0; i < 256; i++) {
        float ang = (float)r * div[i];
        acc = fmaf(sinf(ang), emb_W[(2 * i) * 128 + c], acc);
        acc = fmaf(cosf(ang), emb_W[(2 * i + 1) * 128 + c], acc);
    }
    P[r * 128 + c] = acc;
}

extern "C" void kernel_launch(void *const *d_in, const int *in_sizes, int n_in,
                              void *d_out, int out_size, void *d_ws, size_t ws_size,
                              hipStream_t stream) {
    const float **in = (const float **)d_in;
    float *dwf = (float *)d_ws;
    float *P   = dwf;                  // 2816 floats
    float *FQE = dwf + 2816;           // 960 floats
    float *FSE = dwf + 3776;           // 768 floats
    _Float16 *W = (_Float16 *)(dwf + 4544);

    Args A;
    A.q_t = in[0]; A.skelA = in[1]; A.skelB = in[2];
    A.qe_o_b = in[10]; A.qe_ln_g = in[11]; A.qe_ln_b = in[12];
    A.qe_m1_b = in[14]; A.qe_m2_b = in[16];
    A.se_o_b = in[22]; A.se_ln_g = in[23]; A.se_ln_b = in[24];
    A.se_m1_b = in[26]; A.se_m2_b = in[28];
    A.fqe = FQE; A.fse = FSE;
    A.P = P;
    A.del_W = in[31]; A.del_b = in[32];
    A.quat_mean = in[3]; A.quat_std = in[4];
    A.W = W; A.out = (float *)d_out;

    SplitArgs sa;
    sa.d[0] = { in[7],  64, 192, WOFF_QE_QKV };
    sa.d[1] = { in[9],  64, 256, WOFF_QE_O };
    sa.d[2] = { in[13], 256, 512, WOFF_QE_M1 };
    sa.d[3] = { in[15], 512, 256, WOFF_QE_M2 };
    sa.d[4] = { in[19], 64, 192, WOFF_SE_QKV };
    sa.d[5] = { in[21], 64, 128, WOFF_SE_O };
    sa.d[6] = { in[25], 128, 256, WOFF_SE_M1 };
    sa.d[7] = { in[27], 256, 128, WOFF_SE_M2 };
    sa.d[8] = { in[29], 512, 128, WOFF_EMB };
    sa.out = W;

    FoldArgs fa;
    fa.qe_tokW = in[5];  fa.qe_tokB = in[6];  fa.qe_qkvW = in[7];  fa.qe_qkvB = in[8];
    fa.se_tokW = in[17]; fa.se_tokB = in[18]; fa.se_qkvW = in[19]; fa.se_qkvB = in[20];
    fa.fqe = FQE; fa.fse = FSE;

    int n_items = in_sizes[0] / (NJ * 4);
    int blocks = n_items / 2;          // 2 items per block

    split_kernel<<<dim3(512, 9), 256, 0, stream>>>(sa);
    fold_kernel<<<2, 192, 0, stream>>>(fa);
    pe_emb_kernel<<<NJ, 128, 0, stream>>>(in[29], in[30], P);
    fused_kernel<<<blocks, 256, 0, stream>>>(A);
}